// Round 1
// baseline (276.051 us; speedup 1.0000x reference)
//
#include <hip/hip_runtime.h>

// Separable 5x5 Gaussian blur, sigma=1.1, BORDER_REFLECT_101, NHWC fp32.
// Shape: (64, 384, 512, 3). Row = 512*3 = 1536 floats = 384 float4.
//
// Sliding-window strip version: one block per (batch, 24-row strip);
// 384 threads = one thread per float4 column. Each block iterates 6
// tiles of 4 rows, carrying the 8-row input window in registers, so it
// loads only 4 NEW rows per tile (28 row-loads / 24 output rows = 1.17x
// read amplification vs 2x for the one-shot 4-row tile kernel).
// Per tile: 4 vertical sums -> padded LDS rows (reflect101 edge floats
// written inline by the edge threads, straight from registers) ->
// fully uniform horizontal pass -> nontemporal float4 stores.
// Grid = 1024 blocks = exactly 4 blocks/CU (LDS 24.8KB x4 = 99KB,
// launch_bounds 6 waves/EU = 24 waves/CU). Next-tile loads are issued
// before the vertical compute so HBM latency hides under VALU work.

#define BN 64
#define HN 384
#define WN 512
#define CN 3
#define ROWF (WN * CN)              // 1536 floats per row
#define ROWQ (ROWF / 4)             // 384 float4 per row
#define TH 4                        // rows per tile iteration
#define SROWS 24                    // rows per block strip
#define NITER (SROWS / TH)          // 6 tiles per strip
#define NSTRIP (HN / SROWS)         // 16 strips per image
#define NT 384                      // one thread per float4 column
#define NBLK (BN * NSTRIP)          // 1024 blocks

#define PADQ 2                      // float4 pad each side of an LDS row
#define LROWQ (ROWQ + 2 * PADQ)     // 388 float4
#define LROWF (LROWQ * 4)           // 1552 floats

// Gaussian taps for ksize=5, sigma=1.1 (precomputed, normalized):
#define CW0 0.07076630f
#define CW1 0.24446040f
#define CW2 0.36954650f

// Native clang vector type: __builtin_nontemporal_store requires it
// (HIP's float4 is a class and is rejected).
typedef float vfloat4 __attribute__((ext_vector_type(4)));

__global__ __launch_bounds__(NT, 6) void gauss_blur_fused(
        const float* __restrict__ x, float* __restrict__ out) {
    __shared__ float v[TH * LROWF];   // 24832 B padded vertical-blur tile

    // XCD-contiguous strip swizzle: XCD k (blockIdx%8) gets strips
    // [k*128, (k+1)*128) in linear order -> vertically adjacent strips
    // (4 shared halo rows) run on the same XCD's L2.
    const int bid  = blockIdx.x;
    const int tile = (bid & 7) * (NBLK >> 3) + (bid >> 3);
    const int b    = tile / NSTRIP;
    const int h0   = (tile - b * NSTRIP) * SROWS;   // first output row
    const float* __restrict__ xb = x + (size_t)b * HN * ROWF;
    float* __restrict__ ob = out + (size_t)b * HN * ROWF;

    const int q = threadIdx.x;       // float4 column index, 0..383

    // ---- prologue: load the initial 8-row window (rows h0-2 .. h0+5).
    // Only the low reflect can trigger here (h0+5 <= 365 < 384).
    float4 win[TH + 4];
#pragma unroll
    for (int i = 0; i < TH + 4; ++i) {
        int hs = h0 + i - 2;
        hs = hs < 0 ? -hs : hs;                 // reflect101 low (wave-uniform)
        win[i] = ((const float4*)(xb + (size_t)hs * ROWF))[q];
    }

    for (int t = 0; t < NITER; ++t) {
        const int r0 = h0 + t * TH;

        // ---- issue next tile's 4 row loads early (latency hides under
        // the vertical VALU work below; drained at the barrier anyway).
        float4 nxt[TH];
        if (t + 1 < NITER) {
            const int rb = r0 + TH + 2;         // rows r0+6 .. r0+9
#pragma unroll
            for (int i = 0; i < TH; ++i) {
                int hs = rb + i;
                hs = hs >= HN ? 2 * HN - 2 - hs : hs;   // reflect101 high
                nxt[i] = ((const float4*)(xb + (size_t)hs * ROWF))[q];
            }
        }

        // ---- vertical pass: 4 sums from the 8-row register window.
        // Edge threads also write the reflect101 pads (12 floats/row)
        // straight from registers: interior float F lives at vr[F].
        //   left : vr[-6..-1] <- floats {6,7,8,3,4,5}
        //   right: vr[1536..1541] <- floats {1530,1531,1532,1527,1528,1529}
#pragma unroll
        for (int r = 0; r < TH; ++r) {
            float4 a;
            a.x = CW0 * (win[r].x + win[r + 4].x) +
                  CW1 * (win[r + 1].x + win[r + 3].x) + CW2 * win[r + 2].x;
            a.y = CW0 * (win[r].y + win[r + 4].y) +
                  CW1 * (win[r + 1].y + win[r + 3].y) + CW2 * win[r + 2].y;
            a.z = CW0 * (win[r].z + win[r + 4].z) +
                  CW1 * (win[r + 1].z + win[r + 3].z) + CW2 * win[r + 2].z;
            a.w = CW0 * (win[r].w + win[r + 4].w) +
                  CW1 * (win[r + 1].w + win[r + 3].w) + CW2 * win[r + 2].w;
            float* vr = v + r * LROWF + 4 * PADQ;    // interior base
            ((float4*)vr)[q] = a;
            if (q == 0)        { vr[-3] = a.w; }                      // f3
            else if (q == 1)   { vr[-2] = a.x; vr[-1] = a.y;          // f4,f5
                                 vr[-6] = a.z; vr[-5] = a.w; }        // f6,f7
            else if (q == 2)   { vr[-4] = a.x; }                      // f8
            else if (q == 381) { vr[1539] = a.w; }                    // f1527
            else if (q == 382) { vr[1540] = a.x; vr[1541] = a.y;      // f1528,f1529
                                 vr[1536] = a.z; vr[1537] = a.w; }    // f1530,f1531
            else if (q == 383) { vr[1538] = a.x; }                    // f1532
        }

        // ---- slide the window down 4 rows
#pragma unroll
        for (int i = 0; i < TH; ++i) win[i] = win[i + 4];
#pragma unroll
        for (int i = 0; i < TH; ++i) win[TH + i] = nxt[i];

        __syncthreads();

        // ---- horizontal pass: uniform for all q (pads hold reflected data)
#pragma unroll
        for (int r = 0; r < TH; ++r) {
            const float* vr = v + r * LROWF;   // padded row base
            float wnd[20];                     // padded floats 4q .. 4q+19
#pragma unroll
            for (int j = 0; j < 5; ++j) {
                float4 tq = ((const float4*)vr)[q + j];
                wnd[4 * j + 0] = tq.x;
                wnd[4 * j + 1] = tq.y;
                wnd[4 * j + 2] = tq.z;
                wnd[4 * j + 3] = tq.w;
            }
            vfloat4 res;
#pragma unroll
            for (int j = 0; j < 4; ++j) {
                res[j] =
                    CW0 * (wnd[j + 2] + wnd[j + 14]) +
                    CW1 * (wnd[j + 5] + wnd[j + 11]) +
                    CW2 * wnd[j + 8];
            }
            __builtin_nontemporal_store(res,
                &((vfloat4*)ob)[(size_t)(r0 + r) * ROWQ + q]);
        }

        __syncthreads();   // LDS reuse: next tile's writes must wait
    }
}

extern "C" void kernel_launch(void* const* d_in, const int* in_sizes, int n_in,
                              void* d_out, int out_size, void* d_ws, size_t ws_size,
                              hipStream_t stream) {
    const float* x = (const float*)d_in[0];
    float* out = (float*)d_out;
    gauss_blur_fused<<<dim3(NBLK), dim3(NT), 0, stream>>>(x, out);
}

// Round 2
// 258.583 us; speedup vs baseline: 1.0676x; 1.0676x over previous
//
#include <hip/hip_runtime.h>

// Separable 5x5 Gaussian blur, sigma=1.1, BORDER_REFLECT_101, NHWC fp32.
// Shape: (64, 384, 512, 3). Row = 512*3 = 1536 floats = 384 float4.
//
// Barrier-free per-wave version: one block per (batch, 4-row tile),
// 512 threads = 8 independent waves. Wave w owns 48 output float4
// columns (q0 = 48*w) but loads a full 64-column window (cols q0-2 ..
// q0+61, all 64 lanes, halo included) for 8 input rows. Vertical sums
// go to the wave's PRIVATE LDS strip (window-indexed, 64 float4/row);
// reflect-101 horizontal pads are fixed from the wave's own data; the
// horizontal pass (lanes 0..47) then reads only same-wave LDS. There is
// NO __syncthreads anywhere -- ordering is same-wave lgkmcnt, so waves
// stream independently and HBM latency is hidden by TLP (no block-wide
// stall on the slowest wave's loads). Column overlap between adjacent
// waves is L1-hot (same CU). Nontemporal stores keep input L3-resident;
// XCD swizzle gives each XCD contiguous tiles.

#define BN 64
#define HN 384
#define WN 512
#define CN 3
#define ROWF (WN * CN)              // 1536 floats per row
#define ROWQ (ROWF / 4)             // 384 float4 per row
#define TH 4                        // rows per tile
#define NTILES (HN / TH)            // 96 tiles per image
#define NTHR 512                    // 8 waves per block
#define NBLK (BN * NTILES)          // 6144 blocks

// Gaussian taps for ksize=5, sigma=1.1 (precomputed, normalized):
#define CW0 0.07076630f
#define CW1 0.24446040f
#define CW2 0.36954650f

// Native clang vector type: __builtin_nontemporal_store requires it.
typedef float vfloat4 __attribute__((ext_vector_type(4)));

__global__ __launch_bounds__(NTHR, 6) void gauss_blur_fused(
        const float* __restrict__ x, float* __restrict__ out) {
    // 8 waves * 4 rows * 64 float4 (256 floats) = 32768 B, wave-private strips
    __shared__ float v[8 * 4 * 256];

    // XCD-contiguous tile swizzle: XCD k (blockIdx%8) gets tiles
    // [k*768, (k+1)*768) in linear order.
    const int bid  = blockIdx.x;
    const int tile = (bid & 7) * (NBLK >> 3) + (bid >> 3);
    const int b    = tile / NTILES;
    const int h0   = (tile - b * NTILES) * TH;
    const float* __restrict__ xb = x + (size_t)b * HN * ROWF;
    float* __restrict__ ob = out + ((size_t)b * HN + h0) * ROWF;

    const int wid = threadIdx.x >> 6;    // wave 0..7
    const int l   = threadIdx.x & 63;    // lane
    const int q0  = wid * 48;            // first output float4 column
    int c = q0 - 2 + l;                  // this lane's window column
    c = c < 0 ? 0 : (c > ROWQ - 1 ? ROWQ - 1 : c);   // clamp (pads fix edges)

    // ---- 8-row input window: coalesced float4 loads, all issued up front
    float4 win[8];
#pragma unroll
    for (int i = 0; i < 8; ++i) {
        int hs = h0 + i - 2;
        hs = hs < 0 ? -hs : hs;                 // reflect101 low (wave-uniform)
        hs = hs >= HN ? 2 * HN - 2 - hs : hs;   // reflect101 high
        win[i] = ((const float4*)(xb + (size_t)hs * ROWF))[c];
    }

    float* const vw = v + wid * (TH * 256);   // this wave's LDS strip

    // ---- vertical pass -> wave-private LDS rows (window-indexed)
#pragma unroll
    for (int r = 0; r < TH; ++r) {
        float4 a;
        a.x = CW0 * (win[r].x + win[r + 4].x) +
              CW1 * (win[r + 1].x + win[r + 3].x) + CW2 * win[r + 2].x;
        a.y = CW0 * (win[r].y + win[r + 4].y) +
              CW1 * (win[r + 1].y + win[r + 3].y) + CW2 * win[r + 2].y;
        a.z = CW0 * (win[r].z + win[r + 4].z) +
              CW1 * (win[r + 1].z + win[r + 3].z) + CW2 * win[r + 2].z;
        a.w = CW0 * (win[r].w + win[r + 4].w) +
              CW1 * (win[r + 1].w + win[r + 3].w) + CW2 * win[r + 2].w;
        ((float4*)(vw + r * 256))[l] = a;
    }

    // ---- reflect101 horizontal pads (edge waves only, same-wave LDS dep,
    // no barrier). Window float wf holds global float g = 4*(q0-2) + wf.
    //   wave 0  : g=-6..-1  <- {6,7,8,3,4,5}      => wf 2..7    <- {14,15,16,11,12,13}
    //   wave 7  : g=1536..41<- {1530,31,32,27,28,29}=> wf 200..205 <- {194,195,196,191,192,193}
    if (q0 == 0 && l < TH * 6) {
        int r = l / 6, p = l - 6 * r;
        float* vr = vw + r * 256;
        vr[2 + p] = vr[p < 3 ? 14 + p : 8 + p];
    } else if (q0 == 336 && l < TH * 6) {
        int r = l / 6, p = l - 6 * r;
        float* vr = vw + r * 256;
        vr[200 + p] = vr[p < 3 ? 194 + p : 188 + p];
    }

    // ---- horizontal pass: lanes 0..47 produce output cols q0..q0+47
    if (l < 48) {
#pragma unroll
        for (int r = 0; r < TH; ++r) {
            const float* vr = vw + r * 256;
            float wnd[20];                 // window floats 4l .. 4l+19
#pragma unroll
            for (int k = 0; k < 5; ++k) {
                float4 t = ((const float4*)vr)[l + k];
                wnd[4 * k + 0] = t.x;
                wnd[4 * k + 1] = t.y;
                wnd[4 * k + 2] = t.z;
                wnd[4 * k + 3] = t.w;
            }
            vfloat4 res;
#pragma unroll
            for (int j = 0; j < 4; ++j) {
                res[j] =
                    CW0 * (wnd[j + 2] + wnd[j + 14]) +
                    CW1 * (wnd[j + 5] + wnd[j + 11]) +
                    CW2 * wnd[j + 8];
            }
            __builtin_nontemporal_store(res,
                &((vfloat4*)ob)[r * ROWQ + q0 + l]);
        }
    }
}

extern "C" void kernel_launch(void* const* d_in, const int* in_sizes, int n_in,
                              void* d_out, int out_size, void* d_ws, size_t ws_size,
                              hipStream_t stream) {
    const float* x = (const float*)d_in[0];
    float* out = (float*)d_out;
    gauss_blur_fused<<<dim3(NBLK), dim3(NTHR), 0, stream>>>(x, out);
}

// Round 4
// 247.193 us; speedup vs baseline: 1.1167x; 1.0461x over previous
//
#include <hip/hip_runtime.h>

// Separable 5x5 Gaussian blur, sigma=1.1, BORDER_REFLECT_101, NHWC fp32.
// Shape: (64, 384, 512, 3). Row = 512*3 = 1536 floats = 384 float4.
// NOTE: horizontal taps are stride-3 in floats (per-channel, C=3).
//
// Two-tile pipelined, barrier-free, wave-private LDS. One block per
// (batch, 8-row double tile); 512 threads = 8 waves. Wave w owns 48
// output float4 columns (q0=48w) and loads a 64-column window (cols
// q0-2..q0+61, halo included). All 12 input rows (h0-2..h0+9) are
// loaded up front and PINNED with sched_barrier(0) so the compiler
// cannot sink them: tile-2's 4 loads stay in flight (vmcnt>0) under
// tile-1's whole vertical+horizontal phase. Vertical sums go to the
// wave's PRIVATE LDS strip; reflect-101 horizontal pads fixed from the
// wave's own data; horizontal pass (lanes 0..47) reads same-wave LDS
// only -> NO __syncthreads anywhere. Window rows 4..7 are reused for
// tile 2 (12 loads / 8 output rows = 1.5x demand vs 2x before).
// Nontemporal stores keep input L3-resident; XCD swizzle gives each
// XCD contiguous tiles.

#define BN 64
#define HN 384
#define WN 512
#define CN 3
#define ROWF (WN * CN)              // 1536 floats per row
#define ROWQ (ROWF / 4)             // 384 float4 per row
#define TH 4                        // rows per tile
#define DTH (2 * TH)                // rows per block (double tile)
#define NDT (HN / DTH)              // 48 double-tiles per image
#define NTHR 512                    // 8 waves per block
#define NBLK (BN * NDT)             // 3072 blocks

// Gaussian taps for ksize=5, sigma=1.1 (precomputed, normalized):
#define CW0 0.07076630f
#define CW1 0.24446040f
#define CW2 0.36954650f

// Native clang vector type: __builtin_nontemporal_store requires it.
typedef float vfloat4 __attribute__((ext_vector_type(4)));

__device__ __forceinline__ void vpass(const float4* win, float* vw, int l) {
#pragma unroll
    for (int r = 0; r < TH; ++r) {
        float4 a;
        a.x = CW0 * (win[r].x + win[r + 4].x) +
              CW1 * (win[r + 1].x + win[r + 3].x) + CW2 * win[r + 2].x;
        a.y = CW0 * (win[r].y + win[r + 4].y) +
              CW1 * (win[r + 1].y + win[r + 3].y) + CW2 * win[r + 2].y;
        a.z = CW0 * (win[r].z + win[r + 4].z) +
              CW1 * (win[r + 1].z + win[r + 3].z) + CW2 * win[r + 2].z;
        a.w = CW0 * (win[r].w + win[r + 4].w) +
              CW1 * (win[r + 1].w + win[r + 3].w) + CW2 * win[r + 2].w;
        ((float4*)(vw + r * 256))[l] = a;
    }
}

__device__ __forceinline__ void pads(float* vw, int q0, int l) {
    // reflect101 horizontal pads, window-float indexed (wf = g - 4*q0 + 8):
    //   wave 0: g=-6..-1 <- {6,7,8,3,4,5}          => wf 2..7 <- {14,15,16,11,12,13}
    //   wave 7: g=1536..1541 <- {1530..32,1527..29} => wf 200..205 <- {194,195,196,191,192,193}
    if (q0 == 0 && l < TH * 6) {
        int r = l / 6, p = l - 6 * r;
        float* vr = vw + r * 256;
        vr[2 + p] = vr[p < 3 ? 14 + p : 8 + p];
    } else if (q0 == 336 && l < TH * 6) {
        int r = l / 6, p = l - 6 * r;
        float* vr = vw + r * 256;
        vr[200 + p] = vr[p < 3 ? 194 + p : 188 + p];
    }
}

__device__ __forceinline__ void hpass(const float* vw, float* ob, int q0, int l) {
    if (l < 48) {
#pragma unroll
        for (int r = 0; r < TH; ++r) {
            const float* vr = vw + r * 256;
            float wnd[20];                 // window floats 4l .. 4l+19
#pragma unroll
            for (int k = 0; k < 5; ++k) {
                float4 t = ((const float4*)vr)[l + k];
                wnd[4 * k + 0] = t.x;
                wnd[4 * k + 1] = t.y;
                wnd[4 * k + 2] = t.z;
                wnd[4 * k + 3] = t.w;
            }
            vfloat4 res;
#pragma unroll
            for (int j = 0; j < 4; ++j) {   // stride-3 taps: per-channel
                res[j] =
                    CW0 * (wnd[j + 2] + wnd[j + 14]) +
                    CW1 * (wnd[j + 5] + wnd[j + 11]) +
                    CW2 * wnd[j + 8];
            }
            __builtin_nontemporal_store(res,
                &((vfloat4*)ob)[r * ROWQ + q0 + l]);
        }
    }
}

__global__ __launch_bounds__(NTHR, 6) void gauss_blur_fused(
        const float* __restrict__ x, float* __restrict__ out) {
    // 8 waves * 4 rows * 64 float4 = 32768 B, wave-private strips
    __shared__ float v[8 * 4 * 256];

    // XCD-contiguous tile swizzle: XCD k (blockIdx%8) gets double-tiles
    // [k*384, (k+1)*384) in linear order.
    const int bid  = blockIdx.x;
    const int tile = (bid & 7) * (NBLK >> 3) + (bid >> 3);
    const int b    = tile / NDT;
    const int h0   = (tile - b * NDT) * DTH;
    const float* __restrict__ xb = x + (size_t)b * HN * ROWF;
    float* __restrict__ ob = out + ((size_t)b * HN + h0) * ROWF;

    const int wid = threadIdx.x >> 6;    // wave 0..7
    const int l   = threadIdx.x & 63;    // lane
    const int q0  = wid * 48;            // first output float4 column
    int c = q0 - 2 + l;                  // this lane's window column
    c = c < 0 ? 0 : (c > ROWQ - 1 ? ROWQ - 1 : c);   // clamp (pads fix edges)

    // ---- all 12 window rows (h0-2 .. h0+9), issued up front and pinned
    float4 win[12];
#pragma unroll
    for (int i = 0; i < 12; ++i) {
        int hs = h0 + i - 2;
        hs = hs < 0 ? -hs : hs;                 // reflect101 low (uniform)
        hs = hs >= HN ? 2 * HN - 2 - hs : hs;   // reflect101 high (uniform)
        win[i] = ((const float4*)(xb + (size_t)hs * ROWF))[c];
    }
    __builtin_amdgcn_sched_barrier(0);   // forbid sinking the loads

    float* const vw = v + wid * (TH * 256);   // this wave's LDS strip

    // ---- tile 1: rows h0 .. h0+3 (uses win[0..7]; win[8..11] in flight)
    vpass(win, vw, l);
    pads(vw, q0, l);
    hpass(vw, ob, q0, l);

    // ---- tile 2: rows h0+4 .. h0+7 (uses win[4..11]); same-wave LDS
    // reuse is ordered by lgkmcnt (no cross-wave sharing -> no barrier)
    vpass(win + 4, vw, l);
    pads(vw, q0, l);
    hpass(vw, ob + TH * ROWF, q0, l);
}

extern "C" void kernel_launch(void* const* d_in, const int* in_sizes, int n_in,
                              void* d_out, int out_size, void* d_ws, size_t ws_size,
                              hipStream_t stream) {
    const float* x = (const float*)d_in[0];
    float* out = (float*)d_out;
    gauss_blur_fused<<<dim3(NBLK), dim3(NTHR), 0, stream>>>(x, out);
}